// Round 2
// baseline (67.321 us; speedup 1.0000x reference)
//
#include <hip/hip_runtime.h>

#define TPB 256
#define PRED_CH 30
#define GT_CH 25

// IEEE-exact helpers: prevent fma contraction so the IoU chain matches numpy
// float32 bit-for-bit (argmax flips would cost absmax=1.0 on obj_ij).
__device__ __forceinline__ float mul_rn(float a, float b) { return __fmul_rn(a, b); }
__device__ __forceinline__ float add_rn(float a, float b) { return __fadd_rn(a, b); }
__device__ __forceinline__ float sub_rn(float a, float b) { return __fsub_rn(a, b); }

// (x,y,w,h) normalized -> xyxy pixels; zero box if all inputs zero.
// Matches reference order: cx = 64*(x+gi); W = w*448; xyxy = cx -/+ W/2.
__device__ __forceinline__ void to_xyxy(float x, float y, float w, float h,
                                        float gi, float gj, float o[4]) {
    float cx = mul_rn(64.0f, add_rn(x, gi));
    float cy = mul_rn(64.0f, add_rn(y, gj));
    float W  = mul_rn(w, 448.0f);
    float H  = mul_rn(h, 448.0f);
    float Wh = mul_rn(W, 0.5f);   // exact halving, same as W/2
    float Hh = mul_rn(H, 0.5f);
    o[0] = sub_rn(cx, Wh);
    o[1] = sub_rn(cy, Hh);
    o[2] = add_rn(cx, Wh);
    o[3] = add_rn(cy, Hh);
    if (x == 0.0f && y == 0.0f && w == 0.0f && h == 0.0f) {
        o[0] = o[1] = o[2] = o[3] = 0.0f;
    }
}

__device__ __forceinline__ float iou_box(const float pb[5] /* conf,x,y,w,h */,
                                         const float gb[4], float areag,
                                         float gi, float gj) {
    float p[4];
    to_xyxy(pb[1], pb[2], pb[3], pb[4], gi, gj, p);
    float lx = fmaxf(gb[0], p[0]);
    float ly = fmaxf(gb[1], p[1]);
    float rx = fminf(gb[2], p[2]);
    float ry = fminf(gb[3], p[3]);
    float iw = fmaxf(sub_rn(rx, lx), 0.0f);
    float ih = fmaxf(sub_rn(ry, ly), 0.0f);
    float inter = mul_rn(iw, ih);
    float areap = mul_rn(sub_rn(p[2], p[0]), sub_rn(p[3], p[1]));
    // reference: inter / (area_g + area_p - inter), left-to-right
    float denom = sub_rn(add_rn(areag, areap), inter);
    return __fdiv_rn(inter, denom);
}

__global__ __launch_bounds__(TPB, 5) void yolo_main(const float* __restrict__ pred,
                                                    const float* __restrict__ gt,
                                                    float* __restrict__ out,
                                                    int ncells, float inv_b) {
    // ONE buffer, reused: pred tile first, then gt tile. 30 KB -> 5 blocks/CU
    // (vs 56.8 KB -> 2 blocks/CU last round; occupancy was the bottleneck).
    __shared__ float sbuf[TPB * PRED_CH];   // 30720 B
    __shared__ float wsum[TPB / 64];

    const int tid    = threadIdx.x;
    const int block0 = blockIdx.x * TPB;
    const int cell   = block0 + tid;

    // ---- stage pred tile: 1920 float4, coalesced ----
    {
        const size_t base4 = (size_t)blockIdx.x * (TPB * PRED_CH / 4);
        const float4* p4 = reinterpret_cast<const float4*>(pred) + base4;
        float4* s4 = reinterpret_cast<float4*>(sbuf);
        const size_t n4_total = (size_t)ncells * PRED_CH / 4;
#pragma unroll
        for (int k = 0; k < 8; ++k) {
            int idx = tid + k * TPB;
            if (idx < TPB * PRED_CH / 4 && base4 + idx < n4_total) s4[idx] = p4[idx];
        }
    }
    __syncthreads();

    // ---- pull my 30 pred floats to registers (float2: base is 8B-aligned;
    //      LDS stride 120B -> 2-way bank alias, free) ----
    float P[PRED_CH];
    {
        const float2* p2 = reinterpret_cast<const float2*>(&sbuf[tid * PRED_CH]);
#pragma unroll
        for (int k = 0; k < PRED_CH / 2; ++k) {
            float2 v = p2[k];
            P[2 * k]     = v.x;
            P[2 * k + 1] = v.y;
        }
    }
    __syncthreads();   // everyone done reading before overwrite

    // ---- stage gt tile into the SAME buffer: 1600 float4 ----
    {
        const size_t base4 = (size_t)blockIdx.x * (TPB * GT_CH / 4);
        const float4* g4 = reinterpret_cast<const float4*>(gt) + base4;
        float4* s4 = reinterpret_cast<float4*>(sbuf);
        const size_t n4_total = (size_t)ncells * GT_CH / 4;
#pragma unroll
        for (int k = 0; k < 7; ++k) {
            int idx = tid + k * TPB;
            if (idx < TPB * GT_CH / 4 && base4 + idx < n4_total) s4[idx] = g4[idx];
        }
    }
    __syncthreads();

    float lsum = 0.0f;
    if (cell < ncells) {
        const float* G = &sbuf[tid * GT_CH];  // stride 25: conflict-free

        const float gm = (G[20] == 1.0f) ? 1.0f : 0.0f;

        // class loss: sum_{c<20} (p-g)^2 * mask   (loose threshold, fma ok)
        float cl = 0.0f;
#pragma unroll
        for (int c = 0; c < 20; ++c) {
            float d = P[c] - G[c];
            cl = fmaf(d, d, cl);
        }
        lsum = cl * gm;

        // grid indices: cell = (b*7 + i)*7 + j ; cx uses i (axis1), cy uses j (axis2)
        const int rem = cell % 49;
        const int ii  = rem / 7;
        const float gi = (float)ii;
        const float gj = (float)(rem - ii * 7);

        float gb[4];
        to_xyxy(G[21], G[22], G[23], G[24], gi, gj, gb);
        const float areag = mul_rn(sub_rn(gb[2], gb[0]), sub_rn(gb[3], gb[1]));

        const float iou0 = iou_box(&P[20], gb, areag, gi, gj);
        const float iou1 = iou_box(&P[25], gb, areag, gi, gj);

        // numpy argmax: first max wins on ties
        const int sel = (iou1 > iou0) ? 1 : 0;

        out[1 + 2 * (size_t)cell]     = (sel == 0) ? gm : 0.0f;
        out[1 + 2 * (size_t)cell + 1] = (sel == 1) ? gm : 0.0f;
    }

    // ---- block reduce class loss, one atomic per block ----
#pragma unroll
    for (int off = 32; off > 0; off >>= 1) lsum += __shfl_down(lsum, off);
    const int wid = tid >> 6, lane = tid & 63;
    if (lane == 0) wsum[wid] = lsum;
    __syncthreads();
    if (tid == 0) {
        float s = wsum[0] + wsum[1] + wsum[2] + wsum[3];
        atomicAdd(out, s * inv_b);
    }
}

extern "C" void kernel_launch(void* const* d_in, const int* in_sizes, int n_in,
                              void* d_out, int out_size, void* d_ws, size_t ws_size,
                              hipStream_t stream) {
    const float* pred = (const float*)d_in[0];
    const float* gt   = (const float*)d_in[1];
    float* out = (float*)d_out;

    const int ncells = in_sizes[0] / PRED_CH;      // B*7*7
    const int batch  = ncells / 49;
    const int blocks = (ncells + TPB - 1) / TPB;

    // zero the scalar-loss slot (graph-capture safe: async on stream)
    hipMemsetAsync(d_out, 0, sizeof(float), stream);
    yolo_main<<<blocks, TPB, 0, stream>>>(pred, gt, out, ncells, 1.0f / (float)batch);
}

// Round 3
// 37.873 us; speedup vs baseline: 1.7776x; 1.7776x over previous
//
#include <hip/hip_runtime.h>

#define TPB 256
#define PRED_CH 30
#define GT_CH 25

// IEEE-exact helpers: prevent fma contraction so the IoU chain matches numpy
// float32 bit-for-bit (argmax flips would cost absmax=1.0 on obj_ij).
__device__ __forceinline__ float mul_rn(float a, float b) { return __fmul_rn(a, b); }
__device__ __forceinline__ float add_rn(float a, float b) { return __fadd_rn(a, b); }
__device__ __forceinline__ float sub_rn(float a, float b) { return __fsub_rn(a, b); }

// (x,y,w,h) normalized -> xyxy pixels; zero box if all inputs zero.
// Matches reference order: cx = 64*(x+gi); W = w*448; xyxy = cx -/+ W/2.
__device__ __forceinline__ void to_xyxy(float x, float y, float w, float h,
                                        float gi, float gj, float o[4]) {
    float cx = mul_rn(64.0f, add_rn(x, gi));
    float cy = mul_rn(64.0f, add_rn(y, gj));
    float W  = mul_rn(w, 448.0f);
    float H  = mul_rn(h, 448.0f);
    float Wh = mul_rn(W, 0.5f);   // exact halving, same as W/2
    float Hh = mul_rn(H, 0.5f);
    o[0] = sub_rn(cx, Wh);
    o[1] = sub_rn(cy, Hh);
    o[2] = add_rn(cx, Wh);
    o[3] = add_rn(cy, Hh);
    if (x == 0.0f && y == 0.0f && w == 0.0f && h == 0.0f) {
        o[0] = o[1] = o[2] = o[3] = 0.0f;
    }
}

__device__ __forceinline__ float iou_box(const float pb[5] /* conf,x,y,w,h */,
                                         const float gb[4], float areag,
                                         float gi, float gj) {
    float p[4];
    to_xyxy(pb[1], pb[2], pb[3], pb[4], gi, gj, p);
    float lx = fmaxf(gb[0], p[0]);
    float ly = fmaxf(gb[1], p[1]);
    float rx = fminf(gb[2], p[2]);
    float ry = fminf(gb[3], p[3]);
    float iw = fmaxf(sub_rn(rx, lx), 0.0f);
    float ih = fmaxf(sub_rn(ry, ly), 0.0f);
    float inter = mul_rn(iw, ih);
    float areap = mul_rn(sub_rn(p[2], p[0]), sub_rn(p[3], p[1]));
    // reference: inter / (area_g + area_p - inter), left-to-right
    float denom = sub_rn(add_rn(areag, areap), inter);
    return __fdiv_rn(inter, denom);
}

__global__ __launch_bounds__(TPB, 5) void yolo_main(const float* __restrict__ pred,
                                                    const float* __restrict__ gt,
                                                    float* __restrict__ out,
                                                    float* __restrict__ partials,
                                                    int ncells) {
    // ONE LDS buffer, reused pred-then-gt (31 KB -> 5 blocks/CU).
    __shared__ float sbuf[TPB * PRED_CH];   // 30720 B
    __shared__ float wsum[TPB / 64];

    const int tid    = threadIdx.x;
    const int block0 = blockIdx.x * TPB;
    const int cell   = block0 + tid;

    // ---- stage pred tile: 1920 float4, coalesced ----
    {
        const size_t base4 = (size_t)blockIdx.x * (TPB * PRED_CH / 4);
        const float4* p4 = reinterpret_cast<const float4*>(pred) + base4;
        float4* s4 = reinterpret_cast<float4*>(sbuf);
        const size_t n4_total = (size_t)ncells * PRED_CH / 4;
#pragma unroll
        for (int k = 0; k < 8; ++k) {
            int idx = tid + k * TPB;
            if (idx < TPB * PRED_CH / 4 && base4 + idx < n4_total) s4[idx] = p4[idx];
        }
    }
    __syncthreads();

    // ---- pull my 30 pred floats to registers ----
    float P[PRED_CH];
    {
        const float2* p2 = reinterpret_cast<const float2*>(&sbuf[tid * PRED_CH]);
#pragma unroll
        for (int k = 0; k < PRED_CH / 2; ++k) {
            float2 v = p2[k];
            P[2 * k]     = v.x;
            P[2 * k + 1] = v.y;
        }
    }
    __syncthreads();   // everyone done reading before overwrite

    // ---- stage gt tile into the SAME buffer: 1600 float4 ----
    {
        const size_t base4 = (size_t)blockIdx.x * (TPB * GT_CH / 4);
        const float4* g4 = reinterpret_cast<const float4*>(gt) + base4;
        float4* s4 = reinterpret_cast<float4*>(sbuf);
        const size_t n4_total = (size_t)ncells * GT_CH / 4;
#pragma unroll
        for (int k = 0; k < 7; ++k) {
            int idx = tid + k * TPB;
            if (idx < TPB * GT_CH / 4 && base4 + idx < n4_total) s4[idx] = g4[idx];
        }
    }
    __syncthreads();

    float lsum = 0.0f;
    if (cell < ncells) {
        const float* G = &sbuf[tid * GT_CH];  // stride 25: conflict-free

        const float gm = (G[20] == 1.0f) ? 1.0f : 0.0f;

        // class loss: sum_{c<20} (p-g)^2 * mask   (loose threshold, fma ok)
        float cl = 0.0f;
#pragma unroll
        for (int c = 0; c < 20; ++c) {
            float d = P[c] - G[c];
            cl = fmaf(d, d, cl);
        }
        lsum = cl * gm;

        // grid indices: cell = (b*7 + i)*7 + j ; cx uses i (axis1), cy uses j (axis2)
        const int rem = cell % 49;
        const int ii  = rem / 7;
        const float gi = (float)ii;
        const float gj = (float)(rem - ii * 7);

        float gb[4];
        to_xyxy(G[21], G[22], G[23], G[24], gi, gj, gb);
        const float areag = mul_rn(sub_rn(gb[2], gb[0]), sub_rn(gb[3], gb[1]));

        const float iou0 = iou_box(&P[20], gb, areag, gi, gj);
        const float iou1 = iou_box(&P[25], gb, areag, gi, gj);

        // numpy argmax: first max wins on ties
        const int sel = (iou1 > iou0) ? 1 : 0;

        out[1 + 2 * (size_t)cell]     = (sel == 0) ? gm : 0.0f;
        out[1 + 2 * (size_t)cell + 1] = (sel == 1) ? gm : 0.0f;
    }

    // ---- block reduce class loss; ONE PLAIN STORE per block (no atomics:
    //      3136 same-address device atomics serialized cross-XCD ~= the whole
    //      64 us of rounds 1-2; occupancy-insensitive, which matched obs.) ----
#pragma unroll
    for (int off = 32; off > 0; off >>= 1) lsum += __shfl_down(lsum, off);
    const int wid = tid >> 6, lane = tid & 63;
    if (lane == 0) wsum[wid] = lsum;
    __syncthreads();
    if (tid == 0) {
        partials[blockIdx.x] = wsum[0] + wsum[1] + wsum[2] + wsum[3];
    }
}

// Single-block fixed-order reduction of per-block partials -> out[0].
__global__ __launch_bounds__(256) void yolo_reduce(const float* __restrict__ partials,
                                                   float* __restrict__ out,
                                                   int nblocks, float inv_b) {
    __shared__ float w[4];
    float s = 0.0f;
    for (int i = threadIdx.x; i < nblocks; i += 256) s += partials[i];
#pragma unroll
    for (int off = 32; off > 0; off >>= 1) s += __shfl_down(s, off);
    if ((threadIdx.x & 63) == 0) w[threadIdx.x >> 6] = s;
    __syncthreads();
    if (threadIdx.x == 0) out[0] = (w[0] + w[1] + w[2] + w[3]) * inv_b;
}

extern "C" void kernel_launch(void* const* d_in, const int* in_sizes, int n_in,
                              void* d_out, int out_size, void* d_ws, size_t ws_size,
                              hipStream_t stream) {
    const float* pred = (const float*)d_in[0];
    const float* gt   = (const float*)d_in[1];
    float* out      = (float*)d_out;
    float* partials = (float*)d_ws;   // nblocks floats (~12.5 KB)

    const int ncells = in_sizes[0] / PRED_CH;      // B*7*7
    const int batch  = ncells / 49;
    const int blocks = (ncells + TPB - 1) / TPB;

    yolo_main<<<blocks, TPB, 0, stream>>>(pred, gt, out, partials, ncells);
    yolo_reduce<<<1, 256, 0, stream>>>(partials, out, blocks, 1.0f / (float)batch);
}

// Round 4
// 34.856 us; speedup vs baseline: 1.9314x; 1.0865x over previous
//
#include <hip/hip_runtime.h>

#define TPB 256
#define CPB 128                     // cells per block
#define PRED_CH 30
#define GT_CH 25
#define PRED_F4 (CPB * PRED_CH / 4) // 960 float4 per tile
#define GT_F4   (CPB * GT_CH / 4)   // 800 float4 per tile

// IEEE-exact helpers: prevent fma contraction so the IoU chain matches numpy
// float32 bit-for-bit (argmax flips would cost absmax=1.0 on obj_ij).
__device__ __forceinline__ float mul_rn(float a, float b) { return __fmul_rn(a, b); }
__device__ __forceinline__ float add_rn(float a, float b) { return __fadd_rn(a, b); }
__device__ __forceinline__ float sub_rn(float a, float b) { return __fsub_rn(a, b); }

// async global->LDS, 16B per lane. Linear LDS dest (wave base + lane*16) is
// exactly the HW-supported pattern for our tid+k*TPB staging.
__device__ __forceinline__ void load_lds16(const void* g, void* l) {
    __builtin_amdgcn_global_load_lds(
        (const __attribute__((address_space(1))) void*)g,
        (__attribute__((address_space(3))) void*)l, 16, 0, 0);
}

__device__ __forceinline__ void to_xyxy(float x, float y, float w, float h,
                                        float gi, float gj, float o[4]) {
    float cx = mul_rn(64.0f, add_rn(x, gi));
    float cy = mul_rn(64.0f, add_rn(y, gj));
    float W  = mul_rn(w, 448.0f);
    float H  = mul_rn(h, 448.0f);
    float Wh = mul_rn(W, 0.5f);
    float Hh = mul_rn(H, 0.5f);
    o[0] = sub_rn(cx, Wh);
    o[1] = sub_rn(cy, Hh);
    o[2] = add_rn(cx, Wh);
    o[3] = add_rn(cy, Hh);
    if (x == 0.0f && y == 0.0f && w == 0.0f && h == 0.0f) {
        o[0] = o[1] = o[2] = o[3] = 0.0f;
    }
}

__device__ __forceinline__ float iou_box(const float pb[5] /* conf,x,y,w,h */,
                                         const float gb[4], float areag,
                                         float gi, float gj) {
    float p[4];
    to_xyxy(pb[1], pb[2], pb[3], pb[4], gi, gj, p);
    float lx = fmaxf(gb[0], p[0]);
    float ly = fmaxf(gb[1], p[1]);
    float rx = fminf(gb[2], p[2]);
    float ry = fminf(gb[3], p[3]);
    float iw = fmaxf(sub_rn(rx, lx), 0.0f);
    float ih = fmaxf(sub_rn(ry, ly), 0.0f);
    float inter = mul_rn(iw, ih);
    float areap = mul_rn(sub_rn(p[2], p[0]), sub_rn(p[3], p[1]));
    float denom = sub_rn(add_rn(areag, areap), inter);  // left-to-right, as numpy
    return __fdiv_rn(inter, denom);
}

__global__ __launch_bounds__(TPB, 5) void yolo_main(const float* __restrict__ pred,
                                                    const float* __restrict__ gt,
                                                    float* __restrict__ out,
                                                    float* __restrict__ partials,
                                                    int ncells) {
    // Both tiles resident (28.2 KB -> 5 blocks/CU) => ONE load phase, ONE
    // vmcnt drain, ONE barrier. (Round 3's one-buffer reuse had two serial
    // HBM-latency exposures per block plus a VGPR<->LDS round-trip.)
    __shared__ float spred[CPB * PRED_CH];  // 15360 B
    __shared__ float sgt[CPB * GT_CH];      // 12800 B
    __shared__ float wsum[TPB / 64];

    const int tid  = threadIdx.x;
    const int cell = blockIdx.x * CPB + (tid & (CPB - 1));  // used by tid<CPB

    // ---- stage both tiles, fully async (global_load_lds, 16B/lane) ----
    {
        const size_t pbase4 = (size_t)blockIdx.x * PRED_F4;
        const float4* p4 = reinterpret_cast<const float4*>(pred) + pbase4;
        float4* sp4 = reinterpret_cast<float4*>(spred);
        const size_t pn4 = (size_t)ncells * PRED_CH / 4;
#pragma unroll
        for (int k = 0; k < 4; ++k) {   // 960 / 256 -> 4 guarded slots
            int idx = tid + k * TPB;
            if (idx < PRED_F4 && pbase4 + idx < pn4) load_lds16(p4 + idx, sp4 + idx);
        }
        const size_t gbase4 = (size_t)blockIdx.x * GT_F4;
        const float4* g4 = reinterpret_cast<const float4*>(gt) + gbase4;
        float4* sg4 = reinterpret_cast<float4*>(sgt);
        const size_t gn4 = (size_t)ncells * GT_CH / 4;
#pragma unroll
        for (int k = 0; k < 4; ++k) {   // 800 / 256 -> 4 guarded slots
            int idx = tid + k * TPB;
            if (idx < GT_F4 && gbase4 + idx < gn4) load_lds16(g4 + idx, sg4 + idx);
        }
    }
    __syncthreads();   // compiler emits vmcnt(0) drain here — the ONLY one

    float lsum = 0.0f;
    if (tid < CPB && cell < ncells) {
        const float* P = &spred[tid * PRED_CH];  // stride 30: 2-way alias, free
        const float* G = &sgt[tid * GT_CH];      // stride 25: conflict-free

        const float gm = (G[20] == 1.0f) ? 1.0f : 0.0f;

        float cl = 0.0f;
#pragma unroll
        for (int c = 0; c < 20; ++c) {
            float d = P[c] - G[c];
            cl = fmaf(d, d, cl);
        }
        lsum = cl * gm;

        // cell = (b*7 + i)*7 + j ; cx uses i (axis1), cy uses j (axis2)
        const int rem = cell % 49;
        const int ii  = rem / 7;
        const float gi = (float)ii;
        const float gj = (float)(rem - ii * 7);

        float gb[4];
        to_xyxy(G[21], G[22], G[23], G[24], gi, gj, gb);
        const float areag = mul_rn(sub_rn(gb[2], gb[0]), sub_rn(gb[3], gb[1]));

        float pb0[5] = {P[20], P[21], P[22], P[23], P[24]};
        float pb1[5] = {P[25], P[26], P[27], P[28], P[29]};
        const float iou0 = iou_box(pb0, gb, areag, gi, gj);
        const float iou1 = iou_box(pb1, gb, areag, gi, gj);

        const int sel = (iou1 > iou0) ? 1 : 0;   // numpy argmax: first max wins

        out[1 + 2 * (size_t)cell]     = (sel == 0) ? gm : 0.0f;
        out[1 + 2 * (size_t)cell + 1] = (sel == 1) ? gm : 0.0f;
    }

    // ---- block reduce class loss; ONE plain store per block (no atomics) ----
#pragma unroll
    for (int off = 32; off > 0; off >>= 1) lsum += __shfl_down(lsum, off);
    const int wid = tid >> 6, lane = tid & 63;
    if (lane == 0) wsum[wid] = lsum;
    __syncthreads();
    if (tid == 0) {
        partials[blockIdx.x] = wsum[0] + wsum[1] + wsum[2] + wsum[3];
    }
}

// Single-block fixed-order reduction of per-block partials -> out[0].
// 1024 threads so the strided pass is ~6 loads/thread (short dep chain).
__global__ __launch_bounds__(1024) void yolo_reduce(const float* __restrict__ partials,
                                                    float* __restrict__ out,
                                                    int nblocks, float inv_b) {
    __shared__ float w[16];
    float s = 0.0f;
    for (int i = threadIdx.x; i < nblocks; i += 1024) s += partials[i];
#pragma unroll
    for (int off = 32; off > 0; off >>= 1) s += __shfl_down(s, off);
    if ((threadIdx.x & 63) == 0) w[threadIdx.x >> 6] = s;
    __syncthreads();
    if (threadIdx.x == 0) {
        float t = 0.0f;
#pragma unroll
        for (int k = 0; k < 16; ++k) t += w[k];
        out[0] = t * inv_b;
    }
}

extern "C" void kernel_launch(void* const* d_in, const int* in_sizes, int n_in,
                              void* d_out, int out_size, void* d_ws, size_t ws_size,
                              hipStream_t stream) {
    const float* pred = (const float*)d_in[0];
    const float* gt   = (const float*)d_in[1];
    float* out      = (float*)d_out;
    float* partials = (float*)d_ws;   // nblocks floats (~25 KB)

    const int ncells = in_sizes[0] / PRED_CH;      // B*7*7
    const int batch  = ncells / 49;
    const int blocks = (ncells + CPB - 1) / CPB;

    yolo_main<<<blocks, TPB, 0, stream>>>(pred, gt, out, partials, ncells);
    yolo_reduce<<<1, 1024, 0, stream>>>(partials, out, blocks, 1.0f / (float)batch);
}